// Round 3
// baseline (497.591 us; speedup 1.0000x reference)
//
#include <hip/hip_runtime.h>
#include <hip/hip_cooperative_groups.h>
#include <stdint.h>

namespace cg = cooperative_groups;

// ---------------------------------------------------------------------------
// CascadeGaussianAdapter, single cooperative kernel.
// d_out layout (floats), N = v*hw slots:
//   O0 = 0   : means  (N,3) | O1 = 3N : covs (N,9) | O2 = 12N : sh (N,75)
//   O3 = 87N : opa (N)      | O4 = 88N: scales (N,3)| O5 = 91N : rots (N,4)
//   O6 = 95N : valid (N)
// Phases (grid.sync between):
//   0: zero occlusion bitmaps (v*hw bytes in d_ws) + invert extrinsics
//   k=1..v-1: mark view k's occluded pixels from live input points of views <k
//             (live(i) == !bitmap[i]; view-0 region stays 0)
//   final: one float4 grid-stride masked copy for the whole output
// ---------------------------------------------------------------------------

__device__ void inv4x4(const float* M, float* out) {
    double m[16];
    for (int i = 0; i < 16; ++i) m[i] = (double)M[i];
    double inv[16];
    inv[0]  =  m[5]*m[10]*m[15] - m[5]*m[11]*m[14] - m[9]*m[6]*m[15] + m[9]*m[7]*m[14] + m[13]*m[6]*m[11] - m[13]*m[7]*m[10];
    inv[4]  = -m[4]*m[10]*m[15] + m[4]*m[11]*m[14] + m[8]*m[6]*m[15] - m[8]*m[7]*m[14] - m[12]*m[6]*m[11] + m[12]*m[7]*m[10];
    inv[8]  =  m[4]*m[9]*m[15]  - m[4]*m[11]*m[13] - m[8]*m[5]*m[15] + m[8]*m[7]*m[13] + m[12]*m[5]*m[11] - m[12]*m[7]*m[9];
    inv[12] = -m[4]*m[9]*m[14]  + m[4]*m[10]*m[13] + m[8]*m[5]*m[14] - m[8]*m[6]*m[13] - m[12]*m[5]*m[10] + m[12]*m[6]*m[9];
    inv[1]  = -m[1]*m[10]*m[15] + m[1]*m[11]*m[14] + m[9]*m[2]*m[15] - m[9]*m[3]*m[14] - m[13]*m[2]*m[11] + m[13]*m[3]*m[10];
    inv[5]  =  m[0]*m[10]*m[15] - m[0]*m[11]*m[14] - m[8]*m[2]*m[15] + m[8]*m[3]*m[14] + m[12]*m[2]*m[11] - m[12]*m[3]*m[10];
    inv[9]  = -m[0]*m[9]*m[15]  + m[0]*m[11]*m[13] + m[8]*m[1]*m[15] - m[8]*m[3]*m[13] - m[12]*m[1]*m[11] + m[12]*m[3]*m[9];
    inv[13] =  m[0]*m[9]*m[14]  - m[0]*m[10]*m[13] - m[8]*m[1]*m[14] + m[8]*m[2]*m[13] + m[12]*m[1]*m[10] - m[12]*m[2]*m[9];
    inv[2]  =  m[1]*m[6]*m[15]  - m[1]*m[7]*m[14]  - m[5]*m[2]*m[15] + m[5]*m[3]*m[14] + m[13]*m[2]*m[7]  - m[13]*m[3]*m[6];
    inv[6]  = -m[0]*m[6]*m[15]  + m[0]*m[7]*m[14]  + m[4]*m[2]*m[15] - m[4]*m[3]*m[14] - m[12]*m[2]*m[7]  + m[12]*m[3]*m[6];
    inv[10] =  m[0]*m[5]*m[15]  - m[0]*m[7]*m[13]  - m[4]*m[1]*m[15] + m[4]*m[3]*m[13] + m[12]*m[1]*m[7]  - m[12]*m[3]*m[5];
    inv[14] = -m[0]*m[5]*m[14]  + m[0]*m[6]*m[13]  + m[4]*m[1]*m[14] - m[4]*m[2]*m[13] - m[12]*m[1]*m[6]  + m[12]*m[2]*m[5];
    inv[3]  = -m[1]*m[6]*m[11]  + m[1]*m[7]*m[10]  + m[5]*m[2]*m[11] - m[5]*m[3]*m[10] - m[9]*m[2]*m[7]   + m[9]*m[3]*m[6];
    inv[7]  =  m[0]*m[6]*m[11]  - m[0]*m[7]*m[10]  - m[4]*m[2]*m[11] + m[4]*m[3]*m[10] + m[8]*m[2]*m[7]   - m[8]*m[3]*m[6];
    inv[11] = -m[0]*m[5]*m[11]  + m[0]*m[7]*m[9]   + m[4]*m[1]*m[11] - m[4]*m[3]*m[9]  - m[8]*m[1]*m[7]   + m[8]*m[3]*m[5];
    inv[15] =  m[0]*m[5]*m[10]  - m[0]*m[6]*m[9]   - m[4]*m[1]*m[10] + m[4]*m[2]*m[9]  + m[8]*m[1]*m[6]   - m[8]*m[2]*m[5];
    double det = m[0]*inv[0] + m[1]*inv[4] + m[2]*inv[8] + m[3]*inv[12];
    double idet = 1.0 / det;
    for (int i = 0; i < 16; ++i) out[i] = (float)(inv[i] * idet);
}

__global__ void __launch_bounds__(256, 4) fused_cascade(
        const float* __restrict__ means, const float* __restrict__ covs,
        const float* __restrict__ shs,   const float* __restrict__ opas,
        const float* __restrict__ scales,const float* __restrict__ rots,
        const float* __restrict__ extr,  const float* __restrict__ intr,
        const int* __restrict__ hp, const int* __restrict__ wp,
        float* __restrict__ out, float* __restrict__ w2c_g,
        uint8_t* __restrict__ bitmaps, int nv, int hw) {
#pragma clang fp contract(off)
    cg::grid_group grid = cg::this_grid();
    const long N = (long)nv * hw;
    const int tid = blockIdx.x * blockDim.x + threadIdx.x;
    const int nthreads = gridDim.x * blockDim.x;

    // ---- phase 0: zero bitmaps + invert extrinsics -------------------------
    {
        uint32_t* bw = (uint32_t*)bitmaps;
        int n_words = (int)(N >> 2);
        for (int i = tid; i < n_words; i += nthreads) bw[i] = 0u;
        if (tid < nv) inv4x4(extr + tid * 16, w2c_g + tid * 16);
    }
    grid.sync();

    // ---- mark phases -------------------------------------------------------
    const int w_ = *wp;
    const int h_ = *hp;
    for (int view = 1; view < nv; ++view) {
        const int n_prev = view * hw;
        const float* mv = means + (long)view * hw * 3;
        const float* W  = w2c_g + view * 16;
        const float* K  = intr + view * 9;
        uint8_t* bmo    = bitmaps + (long)view * hw;
        float W0=W[0],W1=W[1],W2=W[2],W3=W[3],W4=W[4],W5=W[5],W6=W[6],W7=W[7],
              W8=W[8],W9=W[9],W10=W[10],W11=W[11];
        float K0=K[0],K1=K[1],K2=K[2],K3=K[3],K4=K[4],K5=K[5];
        for (int i = tid; i < n_prev; i += nthreads) {
            if (bitmaps[i] != 0) continue;       // dropped earlier -> invalid
            float px = means[3 * i + 0];
            float py = means[3 * i + 1];
            float pz = means[3 * i + 2];
            float c0 = W0 * px + W1 * py + W2  * pz + W3;
            float c1 = W4 * px + W5 * py + W6  * pz + W7;
            float c2 = W8 * px + W9 * py + W10 * pz + W11;
            bool vz = c2 > 1e-8f;
            float zz = fmaxf(c2, 1e-8f);
            float xp = c0 / zz;
            float yp = c1 / zz;
            float n0 = (xp * K0 + yp * K1) + K2;
            float n1 = (xp * K3 + yp * K4) + K5;
            bool m = (n0 >= 0.0f) & (n0 < 1.0f) & (n1 >= 0.0f) & (n1 < 1.0f) & vz;
            if (!m) continue;
            int x = (int)floorf(n0 * (float)w_);
            int y = (int)floorf(n1 * (float)h_);
            int pix = y * h_ + x;                // reference uses h here, not w
            pix = min(max(pix, 0), hw - 1);
            float vx = mv[3 * pix + 0];
            float vy = mv[3 * pix + 1];
            float vw = mv[3 * pix + 2];
            float dx = px - vx, dy = py - vy, dz = pz - vw;
            float dist = sqrtf((dx * dx + dy * dy) + dz * dz);
            if (dist <= 0.2f) bmo[pix] = 1;      // benign race: all store 1
        }
        grid.sync();
    }

    // ---- write phase: fused float4 masked copy of the whole output ---------
    {
        const long N4 = N >> 2;
        const long B0 = 3 * N4, B1 = 12 * N4, B2 = 87 * N4, B3 = 88 * N4,
                   B4 = 91 * N4, B5 = 95 * N4, B6 = 96 * N4;
        const float4* m4 = (const float4*)means;
        const float4* c4 = (const float4*)covs;
        const float4* s4 = (const float4*)shs;
        const float4* o4 = (const float4*)opas;
        const float4* l4 = (const float4*)scales;
        const float4* r4 = (const float4*)rots;
        const uint8_t* bm = bitmaps;
        float4* out4 = (float4*)out;
        for (long q = tid; q < B6; q += nthreads) {
            float4 val;
            if (q < B0) {               // means, s=3
                long t = q, e = 4 * t;
                val = m4[t];
                if (bm[(e + 0) / 3]) val.x = 0.f;
                if (bm[(e + 1) / 3]) val.y = 0.f;
                if (bm[(e + 2) / 3]) val.z = 0.f;
                if (bm[(e + 3) / 3]) val.w = 0.f;
            } else if (q < B1) {        // covs, s=9
                long t = q - B0, e = 4 * t;
                val = c4[t];
                if (bm[(e + 0) / 9]) val.x = 0.f;
                if (bm[(e + 1) / 9]) val.y = 0.f;
                if (bm[(e + 2) / 9]) val.z = 0.f;
                if (bm[(e + 3) / 9]) val.w = 0.f;
            } else if (q < B2) {        // sh, s=75
                long t = q - B1, e = 4 * t;
                val = s4[t];
                if (bm[(e + 0) / 75]) val.x = 0.f;
                if (bm[(e + 1) / 75]) val.y = 0.f;
                if (bm[(e + 2) / 75]) val.z = 0.f;
                if (bm[(e + 3) / 75]) val.w = 0.f;
            } else if (q < B3) {        // opacity, s=1
                long t = q - B2, e = 4 * t;
                val = o4[t];
                if (bm[e + 0]) val.x = 0.f;
                if (bm[e + 1]) val.y = 0.f;
                if (bm[e + 2]) val.z = 0.f;
                if (bm[e + 3]) val.w = 0.f;
            } else if (q < B4) {        // scales, s=3
                long t = q - B3, e = 4 * t;
                val = l4[t];
                if (bm[(e + 0) / 3]) val.x = 0.f;
                if (bm[(e + 1) / 3]) val.y = 0.f;
                if (bm[(e + 2) / 3]) val.z = 0.f;
                if (bm[(e + 3) / 3]) val.w = 0.f;
            } else if (q < B5) {        // rots, s=4 -> one point per float4
                long t = q - B4;
                val = r4[t];
                if (bm[t]) val = make_float4(0.f, 0.f, 0.f, 0.f);
            } else {                    // valid, s=1
                long t = q - B5, e = 4 * t;
                val.x = bm[e + 0] ? 0.f : 1.f;
                val.y = bm[e + 1] ? 0.f : 1.f;
                val.z = bm[e + 2] ? 0.f : 1.f;
                val.w = bm[e + 3] ? 0.f : 1.f;
            }
            out4[q] = val;
        }
    }
}

extern "C" void kernel_launch(void* const* d_in, const int* in_sizes, int n_in,
                              void* d_out, int out_size, void* d_ws, size_t ws_size,
                              hipStream_t stream) {
    const float* means  = (const float*)d_in[0];
    const float* covs   = (const float*)d_in[1];
    const float* shs    = (const float*)d_in[2];
    const float* opas   = (const float*)d_in[3];
    const float* scales = (const float*)d_in[4];
    const float* rots   = (const float*)d_in[5];
    const float* extr   = (const float*)d_in[6];
    const float* intr   = (const float*)d_in[7];
    const int*   hp     = (const int*)d_in[8];
    const int*   wp     = (const int*)d_in[9];

    int nv = in_sizes[6] / 16;            // b*v, b==1 here
    int hw = in_sizes[3] / nv;

    float*   w2c     = (float*)d_ws;              // nv*16 floats
    uint8_t* bitmaps = (uint8_t*)d_ws + 1024;     // nv*hw bytes
    float*   out     = (float*)d_out;

    // Cooperative-safe grid: occupancy query × 256 CUs (gfx950).
    int blocksPerCU = 0;
    if (hipOccupancyMaxActiveBlocksPerMultiprocessor(&blocksPerCU,
            (const void*)fused_cascade, 256, 0) != hipSuccess || blocksPerCU <= 0)
        blocksPerCU = 4;
    int grid = blocksPerCU * 256;

    void* args[] = { (void*)&means, (void*)&covs, (void*)&shs, (void*)&opas,
                     (void*)&scales, (void*)&rots, (void*)&extr, (void*)&intr,
                     (void*)&hp, (void*)&wp, (void*)&out, (void*)&w2c,
                     (void*)&bitmaps, (void*)&nv, (void*)&hw };
    hipLaunchCooperativeKernel((void*)fused_cascade, dim3(grid), dim3(256),
                               args, 0, stream);
}

// Round 4
// 286.403 us; speedup vs baseline: 1.7374x; 1.7374x over previous
//
#include <hip/hip_runtime.h>
#include <stdint.h>

// ---------------------------------------------------------------------------
// CascadeGaussianAdapter — ONE normal kernel launch.
//
// Cross-block shared state (occlusion bitmaps, barrier flags) is accessed
// ONLY via device-scope atomics, which execute at the coherent point (LLC) on
// gfx950 — so no cross-XCD cache flushes (the thing that made cooperative
// grid.sync cost ~110us each in round 3) are ever needed.
//
// Grid is fixed at 256 blocks x 256 threads: 1 block/CU is always co-resident
// (VGPR<=512, LDS tiny), so a custom spin barrier cannot deadlock.
//
// Phases (custom barrier between):
//   P0: per-block inv4x4 into LDS + zero bitmap words (atomicExch)
//   Pk (k=1..v-1): mark view k's occluded pixels from live candidates of
//       views <k (liveness = bitmap byte == 0, read via atomicAdd(w,0))
//   PW: per-quad masked copy: thread t copies points 4t..4t+3 (1.5 KB) for
//       all 7 regions, zeroing dropped points; one atomic keep-word read each.
//
// d_out layout (floats), N = v*hw: means(N,3) covs(N,9) sh(N,75) opa(N)
// scales(N,3) rots(N,4) valid(N). Region (N,s) flat == input (v,hw,s) flat.
// d_ws: [0,4K) barrier flags (4 phases x 256 words), [4K, 4K+N/4 words) bitmaps.
// ---------------------------------------------------------------------------

#define NBLOCKS 256
#define NTHREADS 256
#define BAR_MAGIC(p) (0x0C0FFEE1u + (unsigned)(p))

__device__ void inv4x4(const float* M, float* out) {
    double m[16];
    for (int i = 0; i < 16; ++i) m[i] = (double)M[i];
    double inv[16];
    inv[0]  =  m[5]*m[10]*m[15] - m[5]*m[11]*m[14] - m[9]*m[6]*m[15] + m[9]*m[7]*m[14] + m[13]*m[6]*m[11] - m[13]*m[7]*m[10];
    inv[4]  = -m[4]*m[10]*m[15] + m[4]*m[11]*m[14] + m[8]*m[6]*m[15] - m[8]*m[7]*m[14] - m[12]*m[6]*m[11] + m[12]*m[7]*m[10];
    inv[8]  =  m[4]*m[9]*m[15]  - m[4]*m[11]*m[13] - m[8]*m[5]*m[15] + m[8]*m[7]*m[13] + m[12]*m[5]*m[11] - m[12]*m[7]*m[9];
    inv[12] = -m[4]*m[9]*m[14]  + m[4]*m[10]*m[13] + m[8]*m[5]*m[14] - m[8]*m[6]*m[13] - m[12]*m[5]*m[10] + m[12]*m[6]*m[9];
    inv[1]  = -m[1]*m[10]*m[15] + m[1]*m[11]*m[14] + m[9]*m[2]*m[15] - m[9]*m[3]*m[14] - m[13]*m[2]*m[11] + m[13]*m[3]*m[10];
    inv[5]  =  m[0]*m[10]*m[15] - m[0]*m[11]*m[14] - m[8]*m[2]*m[15] + m[8]*m[3]*m[14] + m[12]*m[2]*m[11] - m[12]*m[3]*m[10];
    inv[9]  = -m[0]*m[9]*m[15]  + m[0]*m[11]*m[13] + m[8]*m[1]*m[15] - m[8]*m[3]*m[13] - m[12]*m[1]*m[11] + m[12]*m[3]*m[9];
    inv[13] =  m[0]*m[9]*m[14]  - m[0]*m[10]*m[13] - m[8]*m[1]*m[14] + m[8]*m[2]*m[13] + m[12]*m[1]*m[10] - m[12]*m[2]*m[9];
    inv[2]  =  m[1]*m[6]*m[15]  - m[1]*m[7]*m[14]  - m[5]*m[2]*m[15] + m[5]*m[3]*m[14] + m[13]*m[2]*m[7]  - m[13]*m[3]*m[6];
    inv[6]  = -m[0]*m[6]*m[15]  + m[0]*m[7]*m[14]  + m[4]*m[2]*m[15] - m[4]*m[3]*m[14] - m[12]*m[2]*m[7]  + m[12]*m[3]*m[6];
    inv[10] =  m[0]*m[5]*m[15]  - m[0]*m[7]*m[13]  - m[4]*m[1]*m[15] + m[4]*m[3]*m[13] + m[12]*m[1]*m[7]  - m[12]*m[3]*m[5];
    inv[14] = -m[0]*m[5]*m[14]  + m[0]*m[6]*m[13]  + m[4]*m[1]*m[14] - m[4]*m[2]*m[13] - m[12]*m[1]*m[6]  + m[12]*m[2]*m[5];
    inv[3]  = -m[1]*m[6]*m[11]  + m[1]*m[7]*m[10]  + m[5]*m[2]*m[11] - m[5]*m[3]*m[10] - m[9]*m[2]*m[7]   + m[9]*m[3]*m[6];
    inv[7]  =  m[0]*m[6]*m[11]  - m[0]*m[7]*m[10]  - m[4]*m[2]*m[11] + m[4]*m[3]*m[10] + m[8]*m[2]*m[7]   - m[8]*m[3]*m[6];
    inv[11] = -m[0]*m[5]*m[11]  + m[0]*m[7]*m[9]   + m[4]*m[1]*m[11] - m[4]*m[3]*m[9]  - m[8]*m[1]*m[7]   + m[8]*m[3]*m[5];
    inv[15] =  m[0]*m[5]*m[10]  - m[0]*m[6]*m[9]   - m[4]*m[1]*m[10] + m[4]*m[2]*m[9]  + m[8]*m[1]*m[6]   - m[8]*m[2]*m[5];
    double det = m[0]*inv[0] + m[1]*inv[4] + m[2]*inv[8] + m[3]*inv[12];
    double idet = 1.0 / det;
    for (int i = 0; i < 16; ++i) out[i] = (float)(inv[i] * idet);
}

// Lightweight grid barrier: MAGIC-valued per-block flags, no init required
// (flag arrays are fresh poison each call; MAGIC != 0xAAAAAAAA).
// All prior memory ops of this kernel's phases are device-scope atomics; the
// s_waitcnt(0) guarantees this wave's atomics have executed at the coherent
// point before we signal.
__device__ __forceinline__ void gridbar(uint32_t* __restrict__ flags, int phase) {
    __builtin_amdgcn_s_waitcnt(0);   // drain vmcnt/lgkmcnt for this wave
    __syncthreads();                 // all waves of this block drained
    uint32_t* f = flags + phase * NBLOCKS;
    if (threadIdx.x == 0) atomicExch(&f[blockIdx.x], BAR_MAGIC(phase));
    if (threadIdx.x < 64) {
        for (int i = threadIdx.x; i < NBLOCKS; i += 64) {
            while (atomicAdd(&f[i], 0u) != BAR_MAGIC(phase))
                __builtin_amdgcn_s_sleep(2);
        }
    }
    __syncthreads();
}

template <int S>  // floats per point in this region
__device__ __forceinline__ void copy_region(const float4* __restrict__ in,
                                            float4* __restrict__ out,
                                            long q, const bool* drop) {
    long base = q * S;               // quad q occupies float4 [q*S, q*S+S)
#pragma unroll
    for (int j = 0; j < S; ++j) {
        float4 v = in[base + j];
        v.x = drop[(4 * j + 0) / S] ? 0.f : v.x;
        v.y = drop[(4 * j + 1) / S] ? 0.f : v.y;
        v.z = drop[(4 * j + 2) / S] ? 0.f : v.z;
        v.w = drop[(4 * j + 3) / S] ? 0.f : v.w;
        out[base + j] = v;
    }
}

__global__ void __launch_bounds__(NTHREADS) fused_cascade(
        const float* __restrict__ means, const float* __restrict__ covs,
        const float* __restrict__ shs,   const float* __restrict__ opas,
        const float* __restrict__ scales,const float* __restrict__ rots,
        const float* __restrict__ extr,  const float* __restrict__ intr,
        const int* __restrict__ hp, const int* __restrict__ wp,
        float* __restrict__ out, uint32_t* __restrict__ flags,
        uint32_t* __restrict__ bwords, int nv, int hw) {
#pragma clang fp contract(off)
    const long N = (long)nv * hw;
    const int  n_words = (int)(N >> 2);
    const int  gtid = blockIdx.x * NTHREADS + threadIdx.x;
    const int  gstride = NBLOCKS * NTHREADS;

    __shared__ float sW[8][12];      // top-3 rows of each view's w2c

    // ---- P0: invert extrinsics into LDS + zero bitmap words ---------------
    if (threadIdx.x < nv && threadIdx.x < 8) {
        float tmp[16];
        inv4x4(extr + threadIdx.x * 16, tmp);
        for (int j = 0; j < 12; ++j) sW[threadIdx.x][j] = tmp[j];
    }
    for (int i = gtid; i < n_words; i += gstride) atomicExch(&bwords[i], 0u);
    gridbar(flags, 0);

    // ---- mark phases -------------------------------------------------------
    const int w_ = *wp;
    const int h_ = *hp;
    for (int view = 1; view < nv; ++view) {
        const int n_quads = (view * hw) >> 2;
        const float* mv = means + (long)view * hw * 3;
        const float* K  = intr + view * 9;
        uint32_t* bmo   = bwords + ((long)view * hw >> 2);
        const float W0 = sW[view][0], W1 = sW[view][1], W2  = sW[view][2],  W3  = sW[view][3];
        const float W4 = sW[view][4], W5 = sW[view][5], W6  = sW[view][6],  W7  = sW[view][7];
        const float W8 = sW[view][8], W9 = sW[view][9], W10 = sW[view][10], W11 = sW[view][11];
        const float K0 = K[0], K1 = K[1], K2 = K[2], K3 = K[3], K4 = K[4], K5 = K[5];
        for (int t = gtid; t < n_quads; t += gstride) {
            uint32_t live = atomicAdd(&bwords[t], 0u);   // 4 candidate bytes
            if (live == 0x01010101u) continue;           // all dropped
#pragma unroll
            for (int c = 0; c < 4; ++c) {
                if ((live >> (8 * c)) & 0xFF) continue;  // dropped -> invalid
                int i = 4 * t + c;
                float px = means[3 * i + 0];
                float py = means[3 * i + 1];
                float pz = means[3 * i + 2];
                float c0 = W0 * px + W1 * py + W2  * pz + W3;
                float c1 = W4 * px + W5 * py + W6  * pz + W7;
                float c2 = W8 * px + W9 * py + W10 * pz + W11;
                bool vz = c2 > 1e-8f;
                float zz = fmaxf(c2, 1e-8f);
                float xp = c0 / zz;
                float yp = c1 / zz;
                float n0 = (xp * K0 + yp * K1) + K2;
                float n1 = (xp * K3 + yp * K4) + K5;
                bool m = (n0 >= 0.0f) & (n0 < 1.0f) & (n1 >= 0.0f) & (n1 < 1.0f) & vz;
                if (!m) continue;
                int x = (int)floorf(n0 * (float)w_);
                int y = (int)floorf(n1 * (float)h_);
                int pix = y * h_ + x;            // reference uses h here, not w
                pix = min(max(pix, 0), hw - 1);
                float vx = mv[3 * pix + 0];
                float vy = mv[3 * pix + 1];
                float vw = mv[3 * pix + 2];
                float dx = px - vx, dy = py - vy, dz = pz - vw;
                float dist = sqrtf((dx * dx + dy * dy) + dz * dz);
                if (dist <= 0.2f)
                    atomicOr(&bmo[pix >> 2], 1u << (8 * (pix & 3)));
            }
        }
        gridbar(flags, view);
    }

    // ---- PW: per-quad masked copy of the whole output ----------------------
    {
        const long N4 = N >> 2;
        const float4* m4 = (const float4*)means;
        const float4* c4 = (const float4*)covs;
        const float4* s4 = (const float4*)shs;
        const float4* o4 = (const float4*)opas;
        const float4* l4 = (const float4*)scales;
        const float4* r4 = (const float4*)rots;
        float4* out4 = (float4*)out;
        for (long q = gtid; q < N4; q += gstride) {
            uint32_t km = atomicAdd(&bwords[q], 0u);
            bool drop[4];
            drop[0] = (km & 0x000000FFu) != 0;
            drop[1] = (km & 0x0000FF00u) != 0;
            drop[2] = (km & 0x00FF0000u) != 0;
            drop[3] = (km & 0xFF000000u) != 0;
            copy_region<3>(m4, out4, q, drop);                       // means
            copy_region<9>(c4, out4 + 3 * N4, q, drop);              // covs
            copy_region<75>(s4, out4 + 12 * N4, q, drop);            // sh
            copy_region<1>(o4, out4 + 87 * N4, q, drop);             // opacity
            copy_region<3>(l4, out4 + 88 * N4, q, drop);             // scales
            copy_region<4>(r4, out4 + 91 * N4, q, drop);             // rots
            float4 vd;                                               // valid
            vd.x = drop[0] ? 0.f : 1.f;
            vd.y = drop[1] ? 0.f : 1.f;
            vd.z = drop[2] ? 0.f : 1.f;
            vd.w = drop[3] ? 0.f : 1.f;
            out4[95 * N4 + q] = vd;
        }
    }
}

extern "C" void kernel_launch(void* const* d_in, const int* in_sizes, int n_in,
                              void* d_out, int out_size, void* d_ws, size_t ws_size,
                              hipStream_t stream) {
    const float* means  = (const float*)d_in[0];
    const float* covs   = (const float*)d_in[1];
    const float* shs    = (const float*)d_in[2];
    const float* opas   = (const float*)d_in[3];
    const float* scales = (const float*)d_in[4];
    const float* rots   = (const float*)d_in[5];
    const float* extr   = (const float*)d_in[6];
    const float* intr   = (const float*)d_in[7];
    const int*   hp     = (const int*)d_in[8];
    const int*   wp     = (const int*)d_in[9];

    int nv = in_sizes[6] / 16;            // b*v, b==1 here
    int hw = in_sizes[3] / nv;

    uint32_t* flags  = (uint32_t*)d_ws;                  // 4 * 256 words
    uint32_t* bwords = (uint32_t*)((char*)d_ws + 4096);  // N/4 words

    fused_cascade<<<NBLOCKS, NTHREADS, 0, stream>>>(
        means, covs, shs, opas, scales, rots, extr, intr, hp, wp,
        (float*)d_out, flags, bwords, nv, hw);
}